// Round 4
// baseline (262.762 us; speedup 1.0000x reference)
//
#include <hip/hip_runtime.h>
#include <math.h>

#ifndef M_PI
#define M_PI 3.14159265358979323846
#endif

// Problem constants
#define HH 192
#define WW 192
#define CC 16
#define FF 32
#define BB 8
#define NBI 68        // active frequency box per spatial axis (freqs -34..33)
#define NROW 35       // computed H-spectrum rows: s = 0..34 (rest by conj symmetry)
#define NCOL 69       // computed W-spectrum cols: sj = -34..34 (col = sj+34)
#define ROW0 62       // first centered (pre-fftshift) row of the mask box
#define MASK_T 4560   // (2i-191)^2 + (2j-191)^2 <= 4560  <=>  d/dmax < 0.25 (exact)
#define NWC (WW*CC)   // 3072
#define NPART 4       // h-reduction partials in k_dft_h
#define SCALE (1.0f/1179648.0f)   // 1/(192*192*32) ifft normalization

// Workspace layout (bytes). Lifetime-packed; peak = 55,152,640 B.
#define OFF_TAB  0ull
#define OFF_JMIN 1536ull
#define OFF_RST  1824ull
#define OFF_KQ   4096ull        // 68*68*16*32 float2 = 18,939,904 -> ends 18,944,000
#define OFF_T1   18944000ull    // 4 * 8*35*3072 float2 = 27,525,120 -> ends 46,469,120
#define OFF_T2   46469120ull    // 8*35*69*16 float2 = 2,472,960 -> ends 48,942,080
#define OFF_M2   18944000ull    // reuses T1 (dead after k_dft_w); 9,469,952 -> ends 28,413,952
#define OFF_M3   28413952ull    // 8*68*32*192 float2 = 26,738,688 -> ends 55,152,640 (T1/T2 dead)
#define T1PART   (BB*NROW*NWC)  // float2 elements per h-partial

__device__ __forceinline__ float2 cmul(float2 a, float2 b) {
    return make_float2(a.x*b.x - a.y*b.y, a.x*b.y + a.y*b.x);
}

// K0: 192-root twiddle table (double-precision build) + mask row tables.
__global__ __launch_bounds__(192) void k_tables(float2* __restrict__ tab,
                                                int* __restrict__ jmin,
                                                int* __restrict__ rstart) {
    int t = threadIdx.x;
    if (t < 192) {
        double th = (2.0 * M_PI / 192.0) * (double)t;
        double s, c;
        sincos(th, &s, &c);
        tab[t] = make_float2((float)c, (float)s);   // e^{+2pi i t/192}
    }
    __shared__ int cnt_s[NBI], jmn_s[NBI];
    if (t < NBI) {
        int ii = ROW0 + t;
        int a = 2*ii - 191;
        int rem = MASK_T - a*a;           // always >= 0 for rows 62..129
        int q = (int)sqrtf((float)rem);
        while ((q+1)*(q+1) <= rem) q++;
        while (q > 0 && q*q > rem) q--;
        jmn_s[t] = (192 - q) >> 1;                        // ceil((191-q)/2)
        cnt_s[t] = ((191 + q) >> 1) - ((192 - q) >> 1) + 1;
    }
    __syncthreads();
    if (t == 0) {
        int acc = 0;
        for (int i = 0; i < NBI; i++) {
            rstart[i] = acc;
            acc += cnt_s[i];
            jmin[i] = jmn_s[i];
        }
        // acc == 3576 (= N_ACTIVE / (C*F)), verified analytically.
    }
}

// K1: scatter the flat weights into the 68x68 box AND fold in the C-forward-DFT
// and F-inverse-DFT:  KQ[c,g] = sum_{sc,f} e^{-2pi i c sc/16} K[sc,f] e^{+2pi i f g/32}
__global__ __launch_bounds__(256) void k_densify(
        const float* __restrict__ kr, const float* __restrict__ ki,
        const float2* __restrict__ tab, const int* __restrict__ jmin,
        const int* __restrict__ rstart, float2* __restrict__ KQ) {
    int blk = blockIdx.x;                 // bi*68 + bj
    int bi = blk / NBI, bj = blk - bi*NBI;
    int tid = threadIdx.x;
    float2* KQo = KQ + (size_t)blk * (CC*FF);
    int a = 2*(ROW0+bi) - 191;
    int bc = 2*(ROW0+bj) - 191;
    bool masked = (a*a + bc*bc) <= MASK_T;   // block-uniform
    if (!masked) {
        for (int e = tid; e < CC*FF; e += 256) KQo[e] = make_float2(0.f, 0.f);
        return;
    }
    __shared__ float2 Kc[CC][FF+1];
    __shared__ float2 Kt[CC][FF+1];
    __shared__ float2 tl[192];
    for (int e = tid; e < 192; e += 256) tl[e] = tab[e];
    int rank = rstart[bi] + ((ROW0+bj) - jmin[bi]);
    size_t base = (size_t)rank * (CC*FF);
    for (int e = tid; e < CC*FF; e += 256)
        Kc[e>>5][e&31] = make_float2(kr[base+e], ki[base+e]);
    __syncthreads();
    for (int e = tid; e < CC*FF; e += 256) {      // Kt[cp][f] = DFT16_c
        int cp = e >> 5, f = e & 31;
        float2 acc = make_float2(0.f, 0.f);
        #pragma unroll
        for (int c = 0; c < CC; c++) {
            int tt = (12*c*cp) % 192;             // 2pi/16 = 2pi*12/192
            float2 w = tl[tt];
            float2 v = Kc[c][f];
            acc.x += v.x*w.x + v.y*w.y;           // v * conj(w)
            acc.y += v.y*w.x - v.x*w.y;
        }
        Kt[cp][f] = acc;
    }
    __syncthreads();
    for (int e = tid; e < CC*FF; e += 256) {      // KQ[cp][g] = iDFT32_f
        int cp = e >> 5, g = e & 31;
        float2 acc = make_float2(0.f, 0.f);
        #pragma unroll
        for (int f = 0; f < FF; f++) {
            int tt = (6*f*g) % 192;               // 2pi/32 = 2pi*6/192
            float2 w = tl[tt];
            float2 v = Kt[cp][f];
            acc.x += v.x*w.x - v.y*w.y;           // v * w
            acc.y += v.x*w.y + v.y*w.x;
        }
        KQo[cp*FF + g] = acc;
    }
}

// K_A: partial forward DFT over H at s = 0..34 only (input real -> Hermitian).
// T1[part][b][row][w][c] = sum_{h in part} in[b][h][w][c] * e^{-2pi i s h/192}, s=row
__global__ __launch_bounds__(256) void k_dft_h(
        const float* __restrict__ in, const float2* __restrict__ tab,
        float2* __restrict__ T1) {
    int bg = blockIdx.x;          // 0..8, 4 rows each (row 35 padded off)
    int b  = blockIdx.y;
    int zc = blockIdx.z;          // quarter*NPART + part
    int z  = zc / NPART;
    int part = zc - z*NPART;
    int h0 = part * (HH/NPART);
    int tid = threadIdx.x;
    const float* inb = in + (size_t)b * HH * NWC;
    int wc0 = z * 768 + tid;
    float2 tw[4], r[4];
    #pragma unroll
    for (int u = 0; u < 4; u++) {
        int row = bg*4 + u;
        int s = row < NROW ? row : 0;
        float2 tv = tab[s];
        r[u] = make_float2(tv.x, -tv.y);          // e^{-2pi i s/192}
        float2 t0 = tab[(s*h0) % 192];
        tw[u] = make_float2(t0.x, -t0.y);         // e^{-2pi i s h0/192}
    }
    float2 acc[4][3];
    #pragma unroll
    for (int u = 0; u < 4; u++)
        #pragma unroll
        for (int k = 0; k < 3; k++) acc[u][k] = make_float2(0.f, 0.f);
    for (int h = h0; h < h0 + HH/NPART; h++) {
        const float* row = inb + (size_t)h * NWC + wc0;
        float v0 = row[0];
        float v1 = row[256];
        float v2 = row[512];
        #pragma unroll
        for (int u = 0; u < 4; u++) {
            acc[u][0].x += v0 * tw[u].x; acc[u][0].y += v0 * tw[u].y;
            acc[u][1].x += v1 * tw[u].x; acc[u][1].y += v1 * tw[u].y;
            acc[u][2].x += v2 * tw[u].x; acc[u][2].y += v2 * tw[u].y;
            tw[u] = cmul(tw[u], r[u]);
        }
    }
    #pragma unroll
    for (int u = 0; u < 4; u++) {
        int row = bg*4 + u;
        if (row < NROW) {
            float2* o = T1 + (size_t)part * T1PART + ((size_t)(b*NROW + row)) * NWC + wc0;
            o[0] = acc[u][0]; o[256] = acc[u][1]; o[512] = acc[u][2];
        }
    }
}

// K_B: partial forward DFT over W for the 35 computed rows, 69 cols (sj=-34..34).
// T2[b][row][col][c] = sum_w T1sum[b][row][w][c] * e^{-2pi i (col-34) w/192}
__global__ __launch_bounds__(256) void k_dft_w(
        const float2* __restrict__ T1, const float2* __restrict__ tab,
        float2* __restrict__ T2) {
    int row = blockIdx.x;             // 0..34
    int b   = blockIdx.y;
    int half = blockIdx.z;            // 0: cols 0..34, 1: cols 35..68
    int tid = threadIdx.x;
    __shared__ float2 sh[HH][CC];     // 24 KB
    const float2* src = T1 + ((size_t)(b*NROW + row)) * NWC;
    for (int e = tid; e < NWC; e += 256) {
        float2 a0 = src[e];
        float2 a1 = src[e + T1PART];
        float2 a2 = src[e + 2*T1PART];
        float2 a3 = src[e + 3*T1PART];
        sh[e>>4][e&15] = make_float2(a0.x+a1.x+a2.x+a3.x, a0.y+a1.y+a2.y+a3.y);
    }
    __syncthreads();
    int c = tid >> 4;                 // 0..15
    int bjL = tid & 15;               // 0..15
    float2 tw[3], r[3], acc[3];
    #pragma unroll
    for (int k = 0; k < 3; k++) {
        int off = bjL + 16*k;
        int col = half*35 + off;
        bool valid = (half == 0) ? (off < 35) : (off < 34);
        int sj = (valid ? col : 34) - 34;
        tw[k] = make_float2(1.f, 0.f);
        acc[k] = make_float2(0.f, 0.f);
        int ts = ((sj % 192) + 192) % 192;
        float2 tv = tab[ts];
        r[k] = make_float2(tv.x, -tv.y);
    }
    for (int w = 0; w < HH; w++) {
        float2 av = sh[w][c];
        #pragma unroll
        for (int k = 0; k < 3; k++) {
            acc[k].x += av.x*tw[k].x - av.y*tw[k].y;
            acc[k].y += av.x*tw[k].y + av.y*tw[k].x;
            tw[k] = cmul(tw[k], r[k]);
        }
    }
    float2* dst = T2 + ((size_t)((b*NROW + row)*NCOL)) * CC;
    #pragma unroll
    for (int k = 0; k < 3; k++) {
        int off = bjL + 16*k;
        int col = half*35 + off;
        bool valid = (half == 0) ? (off < 35) : (off < 34);
        if (valid) dst[col*CC + c] = acc[k];
    }
}

// K_M: per-site 16->32 complex matvec; negative-s rows read the conj mirror.
__global__ __launch_bounds__(256) void k_mix(
        const float2* __restrict__ T2, const float2* __restrict__ KQ,
        float2* __restrict__ M2) {
    int site = blockIdx.x;            // bi*68 + bj
    int bi = site / NBI, bj = site - bi*NBI;
    int tid = threadIdx.x;
    int b = tid >> 5;                 // 8 groups of 32 lanes
    int g = tid & 31;
    int row, col;
    bool cj;
    if (bi >= 34) { row = bi - 34; col = bj;      cj = false; }
    else          { row = 34 - bi; col = 68 - bj; cj = true;  }
    const float2* x  = T2 + ((size_t)(b*NROW + row) * NCOL + col) * CC;
    const float2* kq = KQ + (size_t)site * (CC*FF);
    float sgn = cj ? -1.f : 1.f;
    float2 acc = make_float2(0.f, 0.f);
    #pragma unroll
    for (int cp = 0; cp < CC; cp++) {
        float2 xv = x[cp];
        xv.y *= sgn;
        float2 kv = kq[cp*FF + g];
        acc.x += xv.x*kv.x - xv.y*kv.y;
        acc.y += xv.x*kv.y + xv.y*kv.x;
    }
    M2[((size_t)b * (NBI*NBI) + site) * FF + g] = acc;
}

// K_E2: partial inverse DFT over W — lane = y, stream bj, no LDS, no barrier.
// Each wave: fixed (b, bi, g-quad, y-third); M2 reads are wave-uniform
// (broadcast, L1-served); per-lane rotation twiddle e^{+2pi i s_j y/192}.
// Output TRANSPOSED: M3[b][bi][g][y] so lane-y stores are coalesced.
__global__ __launch_bounds__(256) void k_idft_w(
        const float2* __restrict__ M2, const float2* __restrict__ tab,
        float2* __restrict__ M3) {
    int bi = blockIdx.x;
    int b  = blockIdx.y;
    int ythird = blockIdx.z >> 1;     // 0..2
    int ghalf  = blockIdx.z & 1;      // 0..1
    int lane = threadIdx.x & 63;
    int wv   = threadIdx.x >> 6;      // 0..3
    int g0 = (ghalf*4 + wv) * 4;      // 0,4,...,28
    int y  = ythird*64 + lane;

    const float2* m2 = M2 + ((size_t)b*(NBI*NBI) + (size_t)bi*NBI) * FF + g0;
    float2 tw = tab[(158*y) % 192];   // e^{+2pi i (-34) y/192}
    float2 rr = tab[y];               // e^{+2pi i y/192}
    float2 a0 = make_float2(0.f,0.f), a1 = a0, a2 = a0, a3 = a0;
    #pragma unroll 4
    for (int bj = 0; bj < NBI; bj++) {
        const float2* mp = m2 + (size_t)bj*FF;
        float4 f0 = *reinterpret_cast<const float4*>(mp);      // g0, g0+1
        float4 f1 = *reinterpret_cast<const float4*>(mp + 2);  // g0+2, g0+3
        a0.x += f0.x*tw.x - f0.y*tw.y;  a0.y += f0.x*tw.y + f0.y*tw.x;
        a1.x += f0.z*tw.x - f0.w*tw.y;  a1.y += f0.z*tw.y + f0.w*tw.x;
        a2.x += f1.x*tw.x - f1.y*tw.y;  a2.y += f1.x*tw.y + f1.y*tw.x;
        a3.x += f1.z*tw.x - f1.w*tw.y;  a3.y += f1.z*tw.y + f1.w*tw.x;
        tw = cmul(tw, rr);
    }
    float2* o = M3 + (((size_t)(b*NBI + bi))*FF + g0) * HH + y;
    o[0*HH] = a0; o[1*HH] = a1; o[2*HH] = a2; o[3*HH] = a3;
}

// K_E3: partial inverse DFT over H keeping Re only, via (s,-s) Hermitian pairing:
// out += A_p cos(2pi p x/192) - B_p sin(2pi p x/192), p = 0..34.
// M3 layout is [b][bi][g][y] (transposed by k_idft_w).
__global__ __launch_bounds__(192) void k_idft_h(
        const float2* __restrict__ M3, const float2* __restrict__ tab,
        float* __restrict__ out) {
    int y = blockIdx.x;
    int b = blockIdx.y;
    int x0 = blockIdx.z * 96;
    int tid = threadIdx.x;
    __shared__ __align__(16) float2 comb[NROW][FF];   // (A,B) per pair, 8.96 KB
    for (int e = tid; e < NROW*FF; e += 192) {
        int p = e >> 5, g = e & 31;
        float A, Bv;
        if (p == 0) {
            float2 v = M3[(((size_t)(b*NBI + 34))*FF + g)*HH + y];
            A = v.x; Bv = 0.f;
        } else if (p == 34) {
            float2 v = M3[(((size_t)(b*NBI + 0))*FF + g)*HH + y];
            A = v.x; Bv = -v.y;
        } else {
            float2 vp = M3[(((size_t)(b*NBI + 34 + p))*FF + g)*HH + y];
            float2 vm = M3[(((size_t)(b*NBI + 34 - p))*FF + g)*HH + y];
            A = vp.x + vm.x; Bv = vp.y - vm.y;
        }
        comb[p][g] = make_float2(A, Bv);
    }
    __syncthreads();
    int tx = tid >> 3;          // 0..23  (4 x per thread)
    int tg = tid & 7;
    int g0 = tg * 4;
    float2 tw[4], rr[4];
    float acc[4][4];
    #pragma unroll
    for (int j = 0; j < 4; j++) {
        int x = x0 + tx*4 + j;
        tw[j] = make_float2(1.f, 0.f);   // angle p=0
        rr[j] = tab[x];                  // e^{+2pi i x/192} per p step
        #pragma unroll
        for (int q = 0; q < 4; q++) acc[j][q] = 0.f;
    }
    for (int p = 0; p < NROW; p++) {
        float4 f0 = *reinterpret_cast<const float4*>(&comb[p][g0]);     // A0,B0,A1,B1
        float4 f1 = *reinterpret_cast<const float4*>(&comb[p][g0+2]);   // A2,B2,A3,B3
        #pragma unroll
        for (int j = 0; j < 4; j++) {
            float2 t = tw[j];
            acc[j][0] += f0.x*t.x - f0.y*t.y;
            acc[j][1] += f0.z*t.x - f0.w*t.y;
            acc[j][2] += f1.x*t.x - f1.y*t.y;
            acc[j][3] += f1.z*t.x - f1.w*t.y;
            tw[j] = cmul(t, rr[j]);
        }
    }
    #pragma unroll
    for (int j = 0; j < 4; j++) {
        int x = x0 + tx*4 + j;
        float4 o;
        o.x = acc[j][0]*SCALE; o.y = acc[j][1]*SCALE;
        o.z = acc[j][2]*SCALE; o.w = acc[j][3]*SCALE;
        *reinterpret_cast<float4*>(&out[(((size_t)(b*HH + x)) * WW + y) * FF + g0]) = o;
    }
}

extern "C" void kernel_launch(void* const* d_in, const int* in_sizes, int n_in,
                              void* d_out, int out_size, void* d_ws, size_t ws_size,
                              hipStream_t stream) {
    const float* in = (const float*)d_in[0];
    const float* kr = (const float*)d_in[1];
    const float* ki = (const float*)d_in[2];
    float* out = (float*)d_out;
    char* ws = (char*)d_ws;
    float2* tab = (float2*)(ws + OFF_TAB);
    int* jmin   = (int*)(ws + OFF_JMIN);
    int* rst    = (int*)(ws + OFF_RST);
    float2* KQ  = (float2*)(ws + OFF_KQ);
    float2* T1  = (float2*)(ws + OFF_T1);
    float2* T2  = (float2*)(ws + OFF_T2);
    float2* M2  = (float2*)(ws + OFF_M2);   // aliases T1 (dead by then)
    float2* M3  = (float2*)(ws + OFF_M3);   // overlaps T1 tail / T2 (dead by then)

    k_tables <<<1, 192, 0, stream>>>(tab, jmin, rst);
    k_densify<<<NBI*NBI, 256, 0, stream>>>(kr, ki, tab, jmin, rst, KQ);
    k_dft_h  <<<dim3(9, BB, 4*NPART), 256, 0, stream>>>(in, tab, T1);
    k_dft_w  <<<dim3(NROW, BB, 2), 256, 0, stream>>>(T1, tab, T2);
    k_mix    <<<NBI*NBI, 256, 0, stream>>>(T2, KQ, M2);
    k_idft_w <<<dim3(NBI, BB, 6), 256, 0, stream>>>(M2, tab, M3);
    k_idft_h <<<dim3(HH, BB, 2), 192, 0, stream>>>(M3, tab, out);
}

// Round 5
// 163.057 us; speedup vs baseline: 1.6115x; 1.6115x over previous
//
#include <hip/hip_runtime.h>
#include <math.h>

#ifndef M_PI
#define M_PI 3.14159265358979323846
#endif

// Problem constants
#define HH 192
#define WW 192
#define CC 16
#define FF 32
#define BB 8
#define NBI 68        // active frequency box per spatial axis (freqs -34..33)
#define NROW 35       // computed H-spectrum rows: s = 0..34 (rest by conj symmetry)
#define NCOL 69       // computed W-spectrum cols: sj = -34..34 (col = sj+34)
#define ROW0 62       // first centered (pre-fftshift) row of the mask box
#define MASK_T 4560   // (2i-191)^2 + (2j-191)^2 <= 4560  <=>  d/dmax < 0.25 (exact)
#define NWC (WW*CC)   // 3072
#define NPART 2       // h-pair partials in k_dft_h (each covers 48 h-pairs)
#define SCALE (1.0f/1179648.0f)   // 1/(192*192*32) ifft normalization

// Workspace layout (bytes). Lifetime-packed; peak = 55,152,640 B.
#define OFF_TAB  0ull
#define OFF_JMIN 1536ull
#define OFF_RST  1824ull
#define OFF_KQ   4096ull        // 68*68*16*32 float2 = 18,939,904 -> ends 18,944,000
#define OFF_T1   18944000ull    // 2 * 8*35*3072 float2 = 13,762,560 -> ends 32,706,560
#define OFF_T2   32706560ull    // 8*35*69*16 float2 = 2,472,960 -> ends 35,179,520
#define OFF_M2   18944000ull    // reuses T1 (dead after k_dft_w); 9,469,952 -> ends 28,413,952
#define OFF_M3   28413952ull    // 8*68*192*32 float2 = 26,738,688 -> ends 55,152,640 (T1/T2 dead)
#define T1PART   (BB*NROW*NWC)  // float2 elements per h-pair partial (860,160)

__device__ __forceinline__ float2 cmul(float2 a, float2 b) {
    return make_float2(a.x*b.x - a.y*b.y, a.x*b.y + a.y*b.x);
}

// K0: 192-root twiddle table (double-precision build) + mask row tables.
__global__ __launch_bounds__(192) void k_tables(float2* __restrict__ tab,
                                                int* __restrict__ jmin,
                                                int* __restrict__ rstart) {
    int t = threadIdx.x;
    if (t < 192) {
        double th = (2.0 * M_PI / 192.0) * (double)t;
        double s, c;
        sincos(th, &s, &c);
        tab[t] = make_float2((float)c, (float)s);   // e^{+2pi i t/192}
    }
    __shared__ int cnt_s[NBI], jmn_s[NBI];
    if (t < NBI) {
        int ii = ROW0 + t;
        int a = 2*ii - 191;
        int rem = MASK_T - a*a;           // always >= 0 for rows 62..129
        int q = (int)sqrtf((float)rem);
        while ((q+1)*(q+1) <= rem) q++;
        while (q > 0 && q*q > rem) q--;
        jmn_s[t] = (192 - q) >> 1;                        // ceil((191-q)/2)
        cnt_s[t] = ((191 + q) >> 1) - ((192 - q) >> 1) + 1;
    }
    __syncthreads();
    if (t == 0) {
        int acc = 0;
        for (int i = 0; i < NBI; i++) {
            rstart[i] = acc;
            acc += cnt_s[i];
            jmin[i] = jmn_s[i];
        }
        // acc == 3576 (= N_ACTIVE / (C*F)), verified analytically.
    }
}

// K1: scatter the flat weights into the 68x68 box AND fold in the C-forward-DFT
// and F-inverse-DFT:  KQ[c,g] = sum_{sc,f} e^{-2pi i c sc/16} K[sc,f] e^{+2pi i f g/32}
__global__ __launch_bounds__(256) void k_densify(
        const float* __restrict__ kr, const float* __restrict__ ki,
        const float2* __restrict__ tab, const int* __restrict__ jmin,
        const int* __restrict__ rstart, float2* __restrict__ KQ) {
    int blk = blockIdx.x;                 // bi*68 + bj
    int bi = blk / NBI, bj = blk - bi*NBI;
    int tid = threadIdx.x;
    float2* KQo = KQ + (size_t)blk * (CC*FF);
    int a = 2*(ROW0+bi) - 191;
    int bc = 2*(ROW0+bj) - 191;
    bool masked = (a*a + bc*bc) <= MASK_T;   // block-uniform
    if (!masked) {
        for (int e = tid; e < CC*FF; e += 256) KQo[e] = make_float2(0.f, 0.f);
        return;
    }
    __shared__ float2 Kc[CC][FF+1];
    __shared__ float2 Kt[CC][FF+1];
    __shared__ float2 tl[192];
    for (int e = tid; e < 192; e += 256) tl[e] = tab[e];
    int rank = rstart[bi] + ((ROW0+bj) - jmin[bi]);
    size_t base = (size_t)rank * (CC*FF);
    for (int e = tid; e < CC*FF; e += 256)
        Kc[e>>5][e&31] = make_float2(kr[base+e], ki[base+e]);
    __syncthreads();
    for (int e = tid; e < CC*FF; e += 256) {      // Kt[cp][f] = DFT16_c
        int cp = e >> 5, f = e & 31;
        float2 acc = make_float2(0.f, 0.f);
        #pragma unroll
        for (int c = 0; c < CC; c++) {
            int tt = (12*c*cp) % 192;             // 2pi/16 = 2pi*12/192
            float2 w = tl[tt];
            float2 v = Kc[c][f];
            acc.x += v.x*w.x + v.y*w.y;           // v * conj(w)
            acc.y += v.y*w.x - v.x*w.y;
        }
        Kt[cp][f] = acc;
    }
    __syncthreads();
    for (int e = tid; e < CC*FF; e += 256) {      // KQ[cp][g] = iDFT32_f
        int cp = e >> 5, g = e & 31;
        float2 acc = make_float2(0.f, 0.f);
        #pragma unroll
        for (int f = 0; f < FF; f++) {
            int tt = (6*f*g) % 192;               // 2pi/32 = 2pi*6/192
            float2 w = tl[tt];
            float2 v = Kt[cp][f];
            acc.x += v.x*w.x - v.y*w.y;           // v * w
            acc.y += v.x*w.y + v.y*w.x;
        }
        KQo[cp*FF + g] = acc;
    }
}

// K_A: partial forward DFT over H at s = 0..34, radix-2 over h:
// T1(s) = sum_{h=0}^{95} (in[h] + (-1)^s in[h+96]) e^{-2pi i s h/192}
// T1[part][b][row][w][c]: part covers h-pairs [48*part, 48*part+48).
__global__ __launch_bounds__(256) void k_dft_h(
        const float* __restrict__ in, const float2* __restrict__ tab,
        float2* __restrict__ T1) {
    int bg = blockIdx.x;          // 0..8, 4 rows each (row 35 padded off)
    int b  = blockIdx.y;
    int zc = blockIdx.z;          // quarter*NPART + part
    int z  = zc >> 1;
    int part = zc & 1;
    int h0 = part * 48;
    int tid = threadIdx.x;
    const float* inb = in + (size_t)b * HH * NWC;
    int wc0 = z * 768 + tid;
    float2 tw[4], r[4];
    #pragma unroll
    for (int u = 0; u < 4; u++) {
        int row = bg*4 + u;
        int s = row < NROW ? row : 0;
        float2 tv = tab[s];
        r[u] = make_float2(tv.x, -tv.y);          // e^{-2pi i s/192}
        float2 t0 = tab[(s*h0) % 192];
        tw[u] = make_float2(t0.x, -t0.y);         // e^{-2pi i s h0/192}
    }
    float2 acc[4][3];
    #pragma unroll
    for (int u = 0; u < 4; u++)
        #pragma unroll
        for (int k = 0; k < 3; k++) acc[u][k] = make_float2(0.f, 0.f);
    for (int h = h0; h < h0 + 48; h++) {
        const float* rowp = inb + (size_t)h * NWC + wc0;
        const float* pr   = rowp + 96 * NWC;
        float v0 = rowp[0],  v1 = rowp[256],  v2 = rowp[512];
        float w0 = pr[0],    w1 = pr[256],    w2 = pr[512];
        float up0 = v0 + w0, up1 = v1 + w1, up2 = v2 + w2;
        float um0 = v0 - w0, um1 = v1 - w1, um2 = v2 - w2;
        // u even -> row even -> plus class; u odd -> minus class (bg*4 even)
        acc[0][0].x += up0*tw[0].x; acc[0][0].y += up0*tw[0].y;
        acc[0][1].x += up1*tw[0].x; acc[0][1].y += up1*tw[0].y;
        acc[0][2].x += up2*tw[0].x; acc[0][2].y += up2*tw[0].y;
        tw[0] = cmul(tw[0], r[0]);
        acc[1][0].x += um0*tw[1].x; acc[1][0].y += um0*tw[1].y;
        acc[1][1].x += um1*tw[1].x; acc[1][1].y += um1*tw[1].y;
        acc[1][2].x += um2*tw[1].x; acc[1][2].y += um2*tw[1].y;
        tw[1] = cmul(tw[1], r[1]);
        acc[2][0].x += up0*tw[2].x; acc[2][0].y += up0*tw[2].y;
        acc[2][1].x += up1*tw[2].x; acc[2][1].y += up1*tw[2].y;
        acc[2][2].x += up2*tw[2].x; acc[2][2].y += up2*tw[2].y;
        tw[2] = cmul(tw[2], r[2]);
        acc[3][0].x += um0*tw[3].x; acc[3][0].y += um0*tw[3].y;
        acc[3][1].x += um1*tw[3].x; acc[3][1].y += um1*tw[3].y;
        acc[3][2].x += um2*tw[3].x; acc[3][2].y += um2*tw[3].y;
        tw[3] = cmul(tw[3], r[3]);
    }
    #pragma unroll
    for (int u = 0; u < 4; u++) {
        int row = bg*4 + u;
        if (row < NROW) {
            float2* o = T1 + (size_t)part * T1PART + ((size_t)(b*NROW + row)) * NWC + wc0;
            o[0] = acc[u][0]; o[256] = acc[u][1]; o[512] = acc[u][2];
        }
    }
}

// K_B: partial forward DFT over W, radix-2 over w:
// T2(col) = sum_{w=0}^{95} (S[w] +- S[w+96]) e^{-2pi i sj w/192}, class by parity(sj).
__global__ __launch_bounds__(256) void k_dft_w(
        const float2* __restrict__ T1, const float2* __restrict__ tab,
        float2* __restrict__ T2) {
    int row = blockIdx.x;             // 0..34
    int b   = blockIdx.y;
    int half = blockIdx.z;            // 0: cols 0..34, 1: cols 35..68
    int tid = threadIdx.x;
    __shared__ float2 shp[96][CC];    // 12 KB  (S[w] + S[w+96])
    __shared__ float2 shm[96][CC];    // 12 KB  (S[w] - S[w+96])
    const float2* src = T1 + ((size_t)(b*NROW + row)) * NWC;
    for (int e = tid; e < 96*CC; e += 256) {
        float2 a0 = src[e];
        float2 a1 = src[e + T1PART];
        float2 b0 = src[e + 96*CC];
        float2 b1 = src[e + 96*CC + T1PART];
        float Sx = a0.x + a1.x, Sy = a0.y + a1.y;
        float Tx = b0.x + b1.x, Ty = b0.y + b1.y;
        shp[e>>4][e&15] = make_float2(Sx + Tx, Sy + Ty);
        shm[e>>4][e&15] = make_float2(Sx - Tx, Sy - Ty);
    }
    __syncthreads();
    int c = tid >> 4;                 // 0..15
    int bjL = tid & 15;               // 0..15
    // parity(sj) = parity(col) = (half*35 + bjL + 16k) & 1 = (half + bjL) & 1
    const float2* shsel = ((half + bjL) & 1) ? &shm[0][0] : &shp[0][0];
    float2 tw[3], r[3], acc[3];
    #pragma unroll
    for (int k = 0; k < 3; k++) {
        int off = bjL + 16*k;
        int col = half*35 + off;
        bool valid = (half == 0) ? (off < 35) : (off < 34);
        int sj = (valid ? col : 34) - 34;
        tw[k] = make_float2(1.f, 0.f);
        acc[k] = make_float2(0.f, 0.f);
        int ts = ((sj % 192) + 192) % 192;
        float2 tv = tab[ts];
        r[k] = make_float2(tv.x, -tv.y);
    }
    for (int w = 0; w < 96; w++) {
        float2 av = shsel[w*CC + c];
        #pragma unroll
        for (int k = 0; k < 3; k++) {
            acc[k].x += av.x*tw[k].x - av.y*tw[k].y;
            acc[k].y += av.x*tw[k].y + av.y*tw[k].x;
            tw[k] = cmul(tw[k], r[k]);
        }
    }
    float2* dst = T2 + ((size_t)((b*NROW + row)*NCOL)) * CC;
    #pragma unroll
    for (int k = 0; k < 3; k++) {
        int off = bjL + 16*k;
        int col = half*35 + off;
        bool valid = (half == 0) ? (off < 35) : (off < 34);
        if (valid) dst[col*CC + c] = acc[k];
    }
}

// K_M: per-site 16->32 complex matvec; negative-s rows read the conj mirror.
__global__ __launch_bounds__(256) void k_mix(
        const float2* __restrict__ T2, const float2* __restrict__ KQ,
        float2* __restrict__ M2) {
    int site = blockIdx.x;            // bi*68 + bj
    int bi = site / NBI, bj = site - bi*NBI;
    int tid = threadIdx.x;
    int b = tid >> 5;                 // 8 groups of 32 lanes
    int g = tid & 31;
    int row, col;
    bool cj;
    if (bi >= 34) { row = bi - 34; col = bj;      cj = false; }
    else          { row = 34 - bi; col = 68 - bj; cj = true;  }
    const float2* x  = T2 + ((size_t)(b*NROW + row) * NCOL + col) * CC;
    const float2* kq = KQ + (size_t)site * (CC*FF);
    float sgn = cj ? -1.f : 1.f;
    float2 acc = make_float2(0.f, 0.f);
    #pragma unroll
    for (int cp = 0; cp < CC; cp++) {
        float2 xv = x[cp];
        xv.y *= sgn;
        float2 kv = kq[cp*FF + g];
        acc.x += xv.x*kv.x - xv.y*kv.y;
        acc.y += xv.x*kv.y + xv.y*kv.x;
    }
    M2[((size_t)b * (NBI*NBI) + site) * FF + g] = acc;
}

// K_E2: inverse DFT over W, streaming (no LDS/barrier) + radix-2 over y:
// thread ~ (y in [0,96), g-quad); M2 reads wave-uniform broadcast; even/odd-bj
// accumulators give M3[y] = E + O and M3[y+96] = E - O (since (-1)^(bj-34)).
// M3 layout (restored): [b][bi][y][g].
__global__ __launch_bounds__(192) void k_idft_w(
        const float2* __restrict__ M2, const float2* __restrict__ tab,
        float2* __restrict__ M3) {
    int bi = blockIdx.x;
    int b  = blockIdx.y;
    int tid = threadIdx.x;
    int y    = tid % 96;
    int gsel = tid / 96;              // 0..1
    int g0 = (blockIdx.z*2 + gsel) * 4;   // 0,4,...,28
    const float2* m2 = M2 + ((size_t)b*(NBI*NBI) + (size_t)bi*NBI) * FF + g0;
    float2 tw = tab[(158*y) % 192];   // e^{+2pi i (-34) y/192}
    float2 rr = tab[y];               // e^{+2pi i y/192}
    float2 e0 = make_float2(0.f,0.f), e1 = e0, e2 = e0, e3 = e0;
    float2 o0 = e0, o1 = e0, o2 = e0, o3 = e0;
    for (int bj = 0; bj < NBI; bj += 2) {
        const float2* mp = m2 + (size_t)bj*FF;
        float4 f0 = *reinterpret_cast<const float4*>(mp);      // g0, g0+1
        float4 f1 = *reinterpret_cast<const float4*>(mp + 2);  // g0+2, g0+3
        e0.x += f0.x*tw.x - f0.y*tw.y;  e0.y += f0.x*tw.y + f0.y*tw.x;
        e1.x += f0.z*tw.x - f0.w*tw.y;  e1.y += f0.z*tw.y + f0.w*tw.x;
        e2.x += f1.x*tw.x - f1.y*tw.y;  e2.y += f1.x*tw.y + f1.y*tw.x;
        e3.x += f1.z*tw.x - f1.w*tw.y;  e3.y += f1.z*tw.y + f1.w*tw.x;
        tw = cmul(tw, rr);
        const float2* mq = mp + FF;
        float4 h0 = *reinterpret_cast<const float4*>(mq);
        float4 h1 = *reinterpret_cast<const float4*>(mq + 2);
        o0.x += h0.x*tw.x - h0.y*tw.y;  o0.y += h0.x*tw.y + h0.y*tw.x;
        o1.x += h0.z*tw.x - h0.w*tw.y;  o1.y += h0.z*tw.y + h0.w*tw.x;
        o2.x += h1.x*tw.x - h1.y*tw.y;  o2.y += h1.x*tw.y + h1.y*tw.x;
        o3.x += h1.z*tw.x - h1.w*tw.y;  o3.y += h1.z*tw.y + h1.w*tw.x;
        tw = cmul(tw, rr);
    }
    float2* oa = M3 + (((size_t)(b*NBI + bi))*HH + y)*FF + g0;
    float2* ob = oa + 96*FF;
    oa[0] = make_float2(e0.x+o0.x, e0.y+o0.y);
    oa[1] = make_float2(e1.x+o1.x, e1.y+o1.y);
    oa[2] = make_float2(e2.x+o2.x, e2.y+o2.y);
    oa[3] = make_float2(e3.x+o3.x, e3.y+o3.y);
    ob[0] = make_float2(e0.x-o0.x, e0.y-o0.y);
    ob[1] = make_float2(e1.x-o1.x, e1.y-o1.y);
    ob[2] = make_float2(e2.x-o2.x, e2.y-o2.y);
    ob[3] = make_float2(e3.x-o3.x, e3.y-o3.y);
}

// K_E3: inverse DFT over H keeping Re only, Hermitian (s,-s) pairing AND
// radix-2 over x: even/odd-p accumulators give out(x) = E+O, out(x+96) = E-O.
// comb[p][g] = (A,B):  contribution = A*cos(2pi p x/192) - B*sin(...).
__global__ __launch_bounds__(256) void k_idft_h(
        const float2* __restrict__ M3, const float2* __restrict__ tab,
        float* __restrict__ out) {
    int y = blockIdx.x;
    int b = blockIdx.y;
    int tid = threadIdx.x;
    __shared__ __align__(16) float2 comb[NROW][FF];   // (A,B) per pair, 8.96 KB
    for (int e = tid; e < NROW*FF; e += 256) {
        int p = e >> 5, g = e & 31;
        float A, Bv;
        if (p == 0) {
            float2 v = M3[(((size_t)(b*NBI + 34))*HH + y)*FF + g];
            A = v.x; Bv = 0.f;
        } else if (p == 34) {
            float2 v = M3[(((size_t)(b*NBI + 0))*HH + y)*FF + g];
            A = v.x; Bv = -v.y;
        } else {
            float2 vp = M3[(((size_t)(b*NBI + 34 + p))*HH + y)*FF + g];
            float2 vm = M3[(((size_t)(b*NBI + 34 - p))*HH + y)*FF + g];
            A = vp.x + vm.x; Bv = vp.y - vm.y;
        }
        comb[p][g] = make_float2(A, Bv);
    }
    __syncthreads();
    int tx = tid >> 3;          // 0..31  (3 x-pairs per thread: x = tx*3+j)
    int tg = tid & 7;
    int g0 = tg * 4;
    float2 tw[3], rr[3];
    float ae[3][4], ao[3][4];
    #pragma unroll
    for (int j = 0; j < 3; j++) {
        int x = tx*3 + j;
        tw[j] = make_float2(1.f, 0.f);   // angle p=0
        rr[j] = tab[x];                  // e^{+2pi i x/192} per p step
        #pragma unroll
        for (int q = 0; q < 4; q++) { ae[j][q] = 0.f; ao[j][q] = 0.f; }
    }
    for (int p = 0; p < 34; p += 2) {
        float4 f0 = *reinterpret_cast<const float4*>(&comb[p][g0]);     // A0,B0,A1,B1
        float4 f1 = *reinterpret_cast<const float4*>(&comb[p][g0+2]);   // A2,B2,A3,B3
        #pragma unroll
        for (int j = 0; j < 3; j++) {
            float2 t = tw[j];
            ae[j][0] += f0.x*t.x - f0.y*t.y;
            ae[j][1] += f0.z*t.x - f0.w*t.y;
            ae[j][2] += f1.x*t.x - f1.y*t.y;
            ae[j][3] += f1.z*t.x - f1.w*t.y;
            tw[j] = cmul(t, rr[j]);
        }
        float4 h0 = *reinterpret_cast<const float4*>(&comb[p+1][g0]);
        float4 h1 = *reinterpret_cast<const float4*>(&comb[p+1][g0+2]);
        #pragma unroll
        for (int j = 0; j < 3; j++) {
            float2 t = tw[j];
            ao[j][0] += h0.x*t.x - h0.y*t.y;
            ao[j][1] += h0.z*t.x - h0.w*t.y;
            ao[j][2] += h1.x*t.x - h1.y*t.y;
            ao[j][3] += h1.z*t.x - h1.w*t.y;
            tw[j] = cmul(t, rr[j]);
        }
    }
    {   // tail p = 34 (even)
        float4 f0 = *reinterpret_cast<const float4*>(&comb[34][g0]);
        float4 f1 = *reinterpret_cast<const float4*>(&comb[34][g0+2]);
        #pragma unroll
        for (int j = 0; j < 3; j++) {
            float2 t = tw[j];
            ae[j][0] += f0.x*t.x - f0.y*t.y;
            ae[j][1] += f0.z*t.x - f0.w*t.y;
            ae[j][2] += f1.x*t.x - f1.y*t.y;
            ae[j][3] += f1.z*t.x - f1.w*t.y;
        }
    }
    #pragma unroll
    for (int j = 0; j < 3; j++) {
        int x = tx*3 + j;
        float4 oA, oB;
        oA.x = (ae[j][0]+ao[j][0])*SCALE; oA.y = (ae[j][1]+ao[j][1])*SCALE;
        oA.z = (ae[j][2]+ao[j][2])*SCALE; oA.w = (ae[j][3]+ao[j][3])*SCALE;
        oB.x = (ae[j][0]-ao[j][0])*SCALE; oB.y = (ae[j][1]-ao[j][1])*SCALE;
        oB.z = (ae[j][2]-ao[j][2])*SCALE; oB.w = (ae[j][3]-ao[j][3])*SCALE;
        *reinterpret_cast<float4*>(&out[(((size_t)(b*HH + x)) * WW + y) * FF + g0]) = oA;
        *reinterpret_cast<float4*>(&out[(((size_t)(b*HH + x + 96)) * WW + y) * FF + g0]) = oB;
    }
}

extern "C" void kernel_launch(void* const* d_in, const int* in_sizes, int n_in,
                              void* d_out, int out_size, void* d_ws, size_t ws_size,
                              hipStream_t stream) {
    const float* in = (const float*)d_in[0];
    const float* kr = (const float*)d_in[1];
    const float* ki = (const float*)d_in[2];
    float* out = (float*)d_out;
    char* ws = (char*)d_ws;
    float2* tab = (float2*)(ws + OFF_TAB);
    int* jmin   = (int*)(ws + OFF_JMIN);
    int* rst    = (int*)(ws + OFF_RST);
    float2* KQ  = (float2*)(ws + OFF_KQ);
    float2* T1  = (float2*)(ws + OFF_T1);
    float2* T2  = (float2*)(ws + OFF_T2);
    float2* M2  = (float2*)(ws + OFF_M2);   // aliases T1 (dead by then)
    float2* M3  = (float2*)(ws + OFF_M3);   // overlaps T2 (dead by then)

    k_tables <<<1, 192, 0, stream>>>(tab, jmin, rst);
    k_densify<<<NBI*NBI, 256, 0, stream>>>(kr, ki, tab, jmin, rst, KQ);
    k_dft_h  <<<dim3(9, BB, 4*NPART), 256, 0, stream>>>(in, tab, T1);
    k_dft_w  <<<dim3(NROW, BB, 2), 256, 0, stream>>>(T1, tab, T2);
    k_mix    <<<NBI*NBI, 256, 0, stream>>>(T2, KQ, M2);
    k_idft_w <<<dim3(NBI, BB, 4), 192, 0, stream>>>(M2, tab, M3);
    k_idft_h <<<dim3(HH, BB), 256, 0, stream>>>(M3, tab, out);
}

// Round 6
// 158.939 us; speedup vs baseline: 1.6532x; 1.0259x over previous
//
#include <hip/hip_runtime.h>
#include <math.h>

#ifndef M_PI
#define M_PI 3.14159265358979323846
#endif

// Problem constants
#define HH 192
#define WW 192
#define CC 16
#define FF 32
#define BB 8
#define NBI 68        // active frequency box per spatial axis (freqs -34..33)
#define NROW 35       // computed H-spectrum rows: s = 0..34 (rest by conj symmetry)
#define NCOL 69       // computed W-spectrum cols: sj = -34..34 (col = sj+34)
#define ROW0 62       // first centered (pre-fftshift) row of the mask box
#define MASK_T 4560   // (2i-191)^2 + (2j-191)^2 <= 4560  <=>  d/dmax < 0.25 (exact)
#define NWC (WW*CC)   // 3072
#define NPART 2       // h-pair partials in k_dft_h (each covers 48 h-pairs)
#define SCALE (1.0f/1179648.0f)   // 1/(192*192*32) ifft normalization

// Workspace layout (bytes). Lifetime-packed; peak = 55,152,640 B.
#define OFF_TAB  0ull
#define OFF_JMIN 1536ull
#define OFF_RST  1824ull
#define OFF_KQ   4096ull        // 68*68*16*32 float2 = 18,939,904 -> ends 18,944,000
#define OFF_T1   18944000ull    // 2 * 8*35*3072 float2 = 13,762,560 -> ends 32,706,560
#define OFF_T2   32706560ull    // 8*35*69*16 float2 = 2,472,960 -> ends 35,179,520
#define OFF_M2   18944000ull    // reuses T1 (dead after k_dft_w); 9,469,952 -> ends 28,413,952
#define OFF_M3   28413952ull    // 8*68*192*32 float2 = 26,738,688 -> ends 55,152,640 (T1/T2 dead)
#define T1PART   (BB*NROW*NWC)  // float2 elements per h-pair partial (860,160)

__device__ __forceinline__ float2 cmul(float2 a, float2 b) {
    return make_float2(a.x*b.x - a.y*b.y, a.x*b.y + a.y*b.x);
}

// K0: 192-root twiddle table (double-precision build) + mask row tables.
__global__ __launch_bounds__(192) void k_tables(float2* __restrict__ tab,
                                                int* __restrict__ jmin,
                                                int* __restrict__ rstart) {
    int t = threadIdx.x;
    if (t < 192) {
        double th = (2.0 * M_PI / 192.0) * (double)t;
        double s, c;
        sincos(th, &s, &c);
        tab[t] = make_float2((float)c, (float)s);   // e^{+2pi i t/192}
    }
    __shared__ int cnt_s[NBI], jmn_s[NBI];
    if (t < NBI) {
        int ii = ROW0 + t;
        int a = 2*ii - 191;
        int rem = MASK_T - a*a;           // always >= 0 for rows 62..129
        int q = (int)sqrtf((float)rem);
        while ((q+1)*(q+1) <= rem) q++;
        while (q > 0 && q*q > rem) q--;
        jmn_s[t] = (192 - q) >> 1;                        // ceil((191-q)/2)
        cnt_s[t] = ((191 + q) >> 1) - ((192 - q) >> 1) + 1;
    }
    __syncthreads();
    if (t == 0) {
        int acc = 0;
        for (int i = 0; i < NBI; i++) {
            rstart[i] = acc;
            acc += cnt_s[i];
            jmin[i] = jmn_s[i];
        }
        // acc == 3576 (= N_ACTIVE / (C*F)), verified analytically.
    }
}

// K1: scatter the flat weights into the 68x68 box AND fold in the C-forward-DFT
// and F-inverse-DFT:  KQ[c,g] = sum_{sc,f} e^{-2pi i c sc/16} K[sc,f] e^{+2pi i f g/32}
__global__ __launch_bounds__(256) void k_densify(
        const float* __restrict__ kr, const float* __restrict__ ki,
        const float2* __restrict__ tab, const int* __restrict__ jmin,
        const int* __restrict__ rstart, float2* __restrict__ KQ) {
    int blk = blockIdx.x;                 // bi*68 + bj
    int bi = blk / NBI, bj = blk - bi*NBI;
    int tid = threadIdx.x;
    float2* KQo = KQ + (size_t)blk * (CC*FF);
    int a = 2*(ROW0+bi) - 191;
    int bc = 2*(ROW0+bj) - 191;
    bool masked = (a*a + bc*bc) <= MASK_T;   // block-uniform
    if (!masked) {
        for (int e = tid; e < CC*FF; e += 256) KQo[e] = make_float2(0.f, 0.f);
        return;
    }
    __shared__ float2 Kc[CC][FF+1];
    __shared__ float2 Kt[CC][FF+1];
    __shared__ float2 tl[192];
    for (int e = tid; e < 192; e += 256) tl[e] = tab[e];
    int rank = rstart[bi] + ((ROW0+bj) - jmin[bi]);
    size_t base = (size_t)rank * (CC*FF);
    for (int e = tid; e < CC*FF; e += 256)
        Kc[e>>5][e&31] = make_float2(kr[base+e], ki[base+e]);
    __syncthreads();
    for (int e = tid; e < CC*FF; e += 256) {      // Kt[cp][f] = DFT16_c
        int cp = e >> 5, f = e & 31;
        float2 acc = make_float2(0.f, 0.f);
        #pragma unroll
        for (int c = 0; c < CC; c++) {
            int tt = (12*c*cp) % 192;             // 2pi/16 = 2pi*12/192
            float2 w = tl[tt];
            float2 v = Kc[c][f];
            acc.x += v.x*w.x + v.y*w.y;           // v * conj(w)
            acc.y += v.y*w.x - v.x*w.y;
        }
        Kt[cp][f] = acc;
    }
    __syncthreads();
    for (int e = tid; e < CC*FF; e += 256) {      // KQ[cp][g] = iDFT32_f
        int cp = e >> 5, g = e & 31;
        float2 acc = make_float2(0.f, 0.f);
        #pragma unroll
        for (int f = 0; f < FF; f++) {
            int tt = (6*f*g) % 192;               // 2pi/32 = 2pi*6/192
            float2 w = tl[tt];
            float2 v = Kt[cp][f];
            acc.x += v.x*w.x - v.y*w.y;           // v * w
            acc.y += v.x*w.y + v.y*w.x;
        }
        KQo[cp*FF + g] = acc;
    }
}

// K_A: partial forward DFT over H at s = 0..34, radix-2 over h:
// T1(s) = sum_{h=0}^{95} (in[h] + (-1)^s in[h+96]) e^{-2pi i s h/192}
// T1[part][b][row][w][c]: part covers h-pairs [48*part, 48*part+48).
__global__ __launch_bounds__(256) void k_dft_h(
        const float* __restrict__ in, const float2* __restrict__ tab,
        float2* __restrict__ T1) {
    int bg = blockIdx.x;          // 0..8, 4 rows each (row 35 padded off)
    int b  = blockIdx.y;
    int zc = blockIdx.z;          // quarter*NPART + part
    int z  = zc >> 1;
    int part = zc & 1;
    int h0 = part * 48;
    int tid = threadIdx.x;
    const float* inb = in + (size_t)b * HH * NWC;
    int wc0 = z * 768 + tid;
    float2 tw[4], r[4];
    #pragma unroll
    for (int u = 0; u < 4; u++) {
        int row = bg*4 + u;
        int s = row < NROW ? row : 0;
        float2 tv = tab[s];
        r[u] = make_float2(tv.x, -tv.y);          // e^{-2pi i s/192}
        float2 t0 = tab[(s*h0) % 192];
        tw[u] = make_float2(t0.x, -t0.y);         // e^{-2pi i s h0/192}
    }
    float2 acc[4][3];
    #pragma unroll
    for (int u = 0; u < 4; u++)
        #pragma unroll
        for (int k = 0; k < 3; k++) acc[u][k] = make_float2(0.f, 0.f);
    for (int h = h0; h < h0 + 48; h++) {
        const float* rowp = inb + (size_t)h * NWC + wc0;
        const float* pr   = rowp + 96 * NWC;
        float v0 = rowp[0],  v1 = rowp[256],  v2 = rowp[512];
        float w0 = pr[0],    w1 = pr[256],    w2 = pr[512];
        float up0 = v0 + w0, up1 = v1 + w1, up2 = v2 + w2;
        float um0 = v0 - w0, um1 = v1 - w1, um2 = v2 - w2;
        // u even -> row even -> plus class; u odd -> minus class (bg*4 even)
        acc[0][0].x += up0*tw[0].x; acc[0][0].y += up0*tw[0].y;
        acc[0][1].x += up1*tw[0].x; acc[0][1].y += up1*tw[0].y;
        acc[0][2].x += up2*tw[0].x; acc[0][2].y += up2*tw[0].y;
        tw[0] = cmul(tw[0], r[0]);
        acc[1][0].x += um0*tw[1].x; acc[1][0].y += um0*tw[1].y;
        acc[1][1].x += um1*tw[1].x; acc[1][1].y += um1*tw[1].y;
        acc[1][2].x += um2*tw[1].x; acc[1][2].y += um2*tw[1].y;
        tw[1] = cmul(tw[1], r[1]);
        acc[2][0].x += up0*tw[2].x; acc[2][0].y += up0*tw[2].y;
        acc[2][1].x += up1*tw[2].x; acc[2][1].y += up1*tw[2].y;
        acc[2][2].x += up2*tw[2].x; acc[2][2].y += up2*tw[2].y;
        tw[2] = cmul(tw[2], r[2]);
        acc[3][0].x += um0*tw[3].x; acc[3][0].y += um0*tw[3].y;
        acc[3][1].x += um1*tw[3].x; acc[3][1].y += um1*tw[3].y;
        acc[3][2].x += um2*tw[3].x; acc[3][2].y += um2*tw[3].y;
        tw[3] = cmul(tw[3], r[3]);
    }
    #pragma unroll
    for (int u = 0; u < 4; u++) {
        int row = bg*4 + u;
        if (row < NROW) {
            float2* o = T1 + (size_t)part * T1PART + ((size_t)(b*NROW + row)) * NWC + wc0;
            o[0] = acc[u][0]; o[256] = acc[u][1]; o[512] = acc[u][2];
        }
    }
}

// K_B: partial forward DFT over W, radix-2 over w:
// T2(col) = sum_{w=0}^{95} (S[w] +- S[w+96]) e^{-2pi i sj w/192}, class by parity(sj).
// Column dim split 4-ways across blockIdx.z for occupancy.
__global__ __launch_bounds__(256) void k_dft_w(
        const float2* __restrict__ T1, const float2* __restrict__ tab,
        float2* __restrict__ T2) {
    int row = blockIdx.x;             // 0..34
    int b   = blockIdx.y;
    int q   = blockIdx.z;             // col quarter: bases 0,17,35,52
    const int qbase[4] = {0, 17, 35, 52};
    const int qcnt[4]  = {17, 18, 17, 17};
    int base = qbase[q], cnt = qcnt[q];
    int tid = threadIdx.x;
    __shared__ float2 shp[96][CC];    // 12 KB  (S[w] + S[w+96])
    __shared__ float2 shm[96][CC];    // 12 KB  (S[w] - S[w+96])
    const float2* src = T1 + ((size_t)(b*NROW + row)) * NWC;
    for (int e = tid; e < 96*CC; e += 256) {
        float2 a0 = src[e];
        float2 a1 = src[e + T1PART];
        float2 b0 = src[e + 96*CC];
        float2 b1 = src[e + 96*CC + T1PART];
        float Sx = a0.x + a1.x, Sy = a0.y + a1.y;
        float Tx = b0.x + b1.x, Ty = b0.y + b1.y;
        shp[e>>4][e&15] = make_float2(Sx + Tx, Sy + Ty);
        shm[e>>4][e&15] = make_float2(Sx - Tx, Sy - Ty);
    }
    __syncthreads();
    int c = tid >> 4;                 // 0..15
    int bjL = tid & 15;               // 0..15
    // parity(col) = (base + bjL + 16k)&1 = (base + bjL)&1 (constant over k)
    const float2* shsel = ((base + bjL) & 1) ? &shm[0][0] : &shp[0][0];
    float2 tw[2], r[2], acc[2];
    #pragma unroll
    for (int k = 0; k < 2; k++) {
        int off = bjL + 16*k;
        int col = base + off;
        bool valid = off < cnt;
        int sj = (valid ? col : 34) - 34;
        tw[k] = make_float2(1.f, 0.f);
        acc[k] = make_float2(0.f, 0.f);
        int ts = ((sj % 192) + 192) % 192;
        float2 tv = tab[ts];
        r[k] = make_float2(tv.x, -tv.y);
    }
    for (int w = 0; w < 96; w++) {
        float2 av = shsel[w*CC + c];
        #pragma unroll
        for (int k = 0; k < 2; k++) {
            acc[k].x += av.x*tw[k].x - av.y*tw[k].y;
            acc[k].y += av.x*tw[k].y + av.y*tw[k].x;
            tw[k] = cmul(tw[k], r[k]);
        }
    }
    float2* dst = T2 + ((size_t)((b*NROW + row)*NCOL)) * CC;
    #pragma unroll
    for (int k = 0; k < 2; k++) {
        int off = bjL + 16*k;
        int col = base + off;
        if (off < cnt) dst[col*CC + c] = acc[k];
    }
}

// K_M: per-site 16->32 complex matvec; negative-s rows read the conj mirror.
__global__ __launch_bounds__(256) void k_mix(
        const float2* __restrict__ T2, const float2* __restrict__ KQ,
        float2* __restrict__ M2) {
    int site = blockIdx.x;            // bi*68 + bj
    int bi = site / NBI, bj = site - bi*NBI;
    int tid = threadIdx.x;
    int b = tid >> 5;                 // 8 groups of 32 lanes
    int g = tid & 31;
    int row, col;
    bool cj;
    if (bi >= 34) { row = bi - 34; col = bj;      cj = false; }
    else          { row = 34 - bi; col = 68 - bj; cj = true;  }
    const float2* x  = T2 + ((size_t)(b*NROW + row) * NCOL + col) * CC;
    const float2* kq = KQ + (size_t)site * (CC*FF);
    float sgn = cj ? -1.f : 1.f;
    float2 acc = make_float2(0.f, 0.f);
    #pragma unroll
    for (int cp = 0; cp < CC; cp++) {
        float2 xv = x[cp];
        xv.y *= sgn;
        float2 kv = kq[cp*FF + g];
        acc.x += xv.x*kv.x - xv.y*kv.y;
        acc.y += xv.x*kv.y + xv.y*kv.x;
    }
    M2[((size_t)b * (NBI*NBI) + site) * FF + g] = acc;
}

// K_E2: inverse DFT over W, streaming (no LDS/barrier) + radix-2 over y.
// Lane map: gq = tid&7 (g-quad), y = 24*z + (tid>>3) -> stores are 16B
// float4 with 8-lane/256B locality (coalesced), instead of 8B stride-256B.
// M2 reads: 8 distinct 32B-spaced addresses per wave (L1 broadcast-served).
// M3 layout: [b][bi][y][g].
__global__ __launch_bounds__(192) void k_idft_w(
        const float2* __restrict__ M2, const float2* __restrict__ tab,
        float2* __restrict__ M3) {
    int bi = blockIdx.x;
    int b  = blockIdx.y;
    int tid = threadIdx.x;
    int g0 = (tid & 7) * 4;           // 0,4,...,28
    int y  = blockIdx.z * 24 + (tid >> 3);   // 0..95
    const float2* m2 = M2 + ((size_t)b*(NBI*NBI) + (size_t)bi*NBI) * FF + g0;
    float2 tw = tab[(158*y) % 192];   // e^{+2pi i (-34) y/192}
    float2 rr = tab[y];               // e^{+2pi i y/192}
    float2 e0 = make_float2(0.f,0.f), e1 = e0, e2 = e0, e3 = e0;
    float2 o0 = e0, o1 = e0, o2 = e0, o3 = e0;
    for (int bj = 0; bj < NBI; bj += 2) {
        const float2* mp = m2 + (size_t)bj*FF;
        float4 f0 = *reinterpret_cast<const float4*>(mp);      // g0, g0+1
        float4 f1 = *reinterpret_cast<const float4*>(mp + 2);  // g0+2, g0+3
        e0.x += f0.x*tw.x - f0.y*tw.y;  e0.y += f0.x*tw.y + f0.y*tw.x;
        e1.x += f0.z*tw.x - f0.w*tw.y;  e1.y += f0.z*tw.y + f0.w*tw.x;
        e2.x += f1.x*tw.x - f1.y*tw.y;  e2.y += f1.x*tw.y + f1.y*tw.x;
        e3.x += f1.z*tw.x - f1.w*tw.y;  e3.y += f1.z*tw.y + f1.w*tw.x;
        tw = cmul(tw, rr);
        const float2* mq = mp + FF;
        float4 h0 = *reinterpret_cast<const float4*>(mq);
        float4 h1 = *reinterpret_cast<const float4*>(mq + 2);
        o0.x += h0.x*tw.x - h0.y*tw.y;  o0.y += h0.x*tw.y + h0.y*tw.x;
        o1.x += h0.z*tw.x - h0.w*tw.y;  o1.y += h0.z*tw.y + h0.w*tw.x;
        o2.x += h1.x*tw.x - h1.y*tw.y;  o2.y += h1.x*tw.y + h1.y*tw.x;
        o3.x += h1.z*tw.x - h1.w*tw.y;  o3.y += h1.z*tw.y + h1.w*tw.x;
        tw = cmul(tw, rr);
    }
    float2* oa = M3 + (((size_t)(b*NBI + bi))*HH + y)*FF + g0;
    float2* ob = oa + 96*FF;
    float4 A0 = make_float4(e0.x+o0.x, e0.y+o0.y, e1.x+o1.x, e1.y+o1.y);
    float4 A1 = make_float4(e2.x+o2.x, e2.y+o2.y, e3.x+o3.x, e3.y+o3.y);
    float4 B0 = make_float4(e0.x-o0.x, e0.y-o0.y, e1.x-o1.x, e1.y-o1.y);
    float4 B1 = make_float4(e2.x-o2.x, e2.y-o2.y, e3.x-o3.x, e3.y-o3.y);
    *reinterpret_cast<float4*>(oa)     = A0;
    *reinterpret_cast<float4*>(oa + 2) = A1;
    *reinterpret_cast<float4*>(ob)     = B0;
    *reinterpret_cast<float4*>(ob + 2) = B1;
}

// K_E3: inverse DFT over H keeping Re only, Hermitian (s,-s) pairing AND
// radix-2 over x: even/odd-p accumulators give out(x) = E+O, out(x+96) = E-O.
// comb[p][g] = (A,B):  contribution = A*cos(2pi p x/192) - B*sin(...).
__global__ __launch_bounds__(256) void k_idft_h(
        const float2* __restrict__ M3, const float2* __restrict__ tab,
        float* __restrict__ out) {
    int y = blockIdx.x;
    int b = blockIdx.y;
    int tid = threadIdx.x;
    __shared__ __align__(16) float2 comb[NROW][FF];   // (A,B) per pair, 8.96 KB
    for (int e = tid; e < NROW*FF; e += 256) {
        int p = e >> 5, g = e & 31;
        float A, Bv;
        if (p == 0) {
            float2 v = M3[(((size_t)(b*NBI + 34))*HH + y)*FF + g];
            A = v.x; Bv = 0.f;
        } else if (p == 34) {
            float2 v = M3[(((size_t)(b*NBI + 0))*HH + y)*FF + g];
            A = v.x; Bv = -v.y;
        } else {
            float2 vp = M3[(((size_t)(b*NBI + 34 + p))*HH + y)*FF + g];
            float2 vm = M3[(((size_t)(b*NBI + 34 - p))*HH + y)*FF + g];
            A = vp.x + vm.x; Bv = vp.y - vm.y;
        }
        comb[p][g] = make_float2(A, Bv);
    }
    __syncthreads();
    int tx = tid >> 3;          // 0..31  (3 x-pairs per thread: x = tx*3+j)
    int tg = tid & 7;
    int g0 = tg * 4;
    float2 tw[3], rr[3];
    float ae[3][4], ao[3][4];
    #pragma unroll
    for (int j = 0; j < 3; j++) {
        int x = tx*3 + j;
        tw[j] = make_float2(1.f, 0.f);   // angle p=0
        rr[j] = tab[x];                  // e^{+2pi i x/192} per p step
        #pragma unroll
        for (int q = 0; q < 4; q++) { ae[j][q] = 0.f; ao[j][q] = 0.f; }
    }
    for (int p = 0; p < 34; p += 2) {
        float4 f0 = *reinterpret_cast<const float4*>(&comb[p][g0]);     // A0,B0,A1,B1
        float4 f1 = *reinterpret_cast<const float4*>(&comb[p][g0+2]);   // A2,B2,A3,B3
        #pragma unroll
        for (int j = 0; j < 3; j++) {
            float2 t = tw[j];
            ae[j][0] += f0.x*t.x - f0.y*t.y;
            ae[j][1] += f0.z*t.x - f0.w*t.y;
            ae[j][2] += f1.x*t.x - f1.y*t.y;
            ae[j][3] += f1.z*t.x - f1.w*t.y;
            tw[j] = cmul(t, rr[j]);
        }
        float4 h0 = *reinterpret_cast<const float4*>(&comb[p+1][g0]);
        float4 h1 = *reinterpret_cast<const float4*>(&comb[p+1][g0+2]);
        #pragma unroll
        for (int j = 0; j < 3; j++) {
            float2 t = tw[j];
            ao[j][0] += h0.x*t.x - h0.y*t.y;
            ao[j][1] += h0.z*t.x - h0.w*t.y;
            ao[j][2] += h1.x*t.x - h1.y*t.y;
            ao[j][3] += h1.z*t.x - h1.w*t.y;
            tw[j] = cmul(t, rr[j]);
        }
    }
    {   // tail p = 34 (even)
        float4 f0 = *reinterpret_cast<const float4*>(&comb[34][g0]);
        float4 f1 = *reinterpret_cast<const float4*>(&comb[34][g0+2]);
        #pragma unroll
        for (int j = 0; j < 3; j++) {
            float2 t = tw[j];
            ae[j][0] += f0.x*t.x - f0.y*t.y;
            ae[j][1] += f0.z*t.x - f0.w*t.y;
            ae[j][2] += f1.x*t.x - f1.y*t.y;
            ae[j][3] += f1.z*t.x - f1.w*t.y;
        }
    }
    #pragma unroll
    for (int j = 0; j < 3; j++) {
        int x = tx*3 + j;
        float4 oA, oB;
        oA.x = (ae[j][0]+ao[j][0])*SCALE; oA.y = (ae[j][1]+ao[j][1])*SCALE;
        oA.z = (ae[j][2]+ao[j][2])*SCALE; oA.w = (ae[j][3]+ao[j][3])*SCALE;
        oB.x = (ae[j][0]-ao[j][0])*SCALE; oB.y = (ae[j][1]-ao[j][1])*SCALE;
        oB.z = (ae[j][2]-ao[j][2])*SCALE; oB.w = (ae[j][3]-ao[j][3])*SCALE;
        *reinterpret_cast<float4*>(&out[(((size_t)(b*HH + x)) * WW + y) * FF + g0]) = oA;
        *reinterpret_cast<float4*>(&out[(((size_t)(b*HH + x + 96)) * WW + y) * FF + g0]) = oB;
    }
}

extern "C" void kernel_launch(void* const* d_in, const int* in_sizes, int n_in,
                              void* d_out, int out_size, void* d_ws, size_t ws_size,
                              hipStream_t stream) {
    const float* in = (const float*)d_in[0];
    const float* kr = (const float*)d_in[1];
    const float* ki = (const float*)d_in[2];
    float* out = (float*)d_out;
    char* ws = (char*)d_ws;
    float2* tab = (float2*)(ws + OFF_TAB);
    int* jmin   = (int*)(ws + OFF_JMIN);
    int* rst    = (int*)(ws + OFF_RST);
    float2* KQ  = (float2*)(ws + OFF_KQ);
    float2* T1  = (float2*)(ws + OFF_T1);
    float2* T2  = (float2*)(ws + OFF_T2);
    float2* M2  = (float2*)(ws + OFF_M2);   // aliases T1 (dead by then)
    float2* M3  = (float2*)(ws + OFF_M3);   // overlaps T2 (dead by then)

    k_tables <<<1, 192, 0, stream>>>(tab, jmin, rst);
    k_densify<<<NBI*NBI, 256, 0, stream>>>(kr, ki, tab, jmin, rst, KQ);
    k_dft_h  <<<dim3(9, BB, 4*NPART), 256, 0, stream>>>(in, tab, T1);
    k_dft_w  <<<dim3(NROW, BB, 4), 256, 0, stream>>>(T1, tab, T2);
    k_mix    <<<NBI*NBI, 256, 0, stream>>>(T2, KQ, M2);
    k_idft_w <<<dim3(NBI, BB, 4), 192, 0, stream>>>(M2, tab, M3);
    k_idft_h <<<dim3(HH, BB), 256, 0, stream>>>(M3, tab, out);
}

// Round 7
// 155.251 us; speedup vs baseline: 1.6925x; 1.0238x over previous
//
#include <hip/hip_runtime.h>
#include <math.h>

#ifndef M_PI
#define M_PI 3.14159265358979323846
#endif

// Problem constants
#define HH 192
#define WW 192
#define CC 16
#define FF 32
#define BB 8
#define NBI 68        // active frequency box per spatial axis (freqs -34..33)
#define NROW 35       // computed H-spectrum rows: s = 0..34 (rest by conj symmetry)
#define NCOL 69       // computed W-spectrum cols: sj = -34..34 (col = sj+34)
#define ROW0 62       // first centered (pre-fftshift) row of the mask box
#define MASK_T 4560   // (2i-191)^2 + (2j-191)^2 <= 4560  <=>  d/dmax < 0.25 (exact)
#define NWC (WW*CC)   // 3072
#define NPART 2       // h-pair partials in k_dft_h (each covers 48 h-pairs)
#define SCALE (1.0f/1179648.0f)   // 1/(192*192*32) ifft normalization

// Workspace layout (bytes). Lifetime-packed; peak = 55,152,640 B.
#define OFF_TAB  0ull
#define OFF_JMIN 1536ull
#define OFF_RST  1824ull
#define OFF_KQ   4096ull        // 68*68*16*32 float2 = 18,939,904 -> ends 18,944,000
#define OFF_T1   18944000ull    // 2 * 8*35*3072 float2 = 13,762,560 -> ends 32,706,560
#define OFF_T2   32706560ull    // 8*35*69*16 float2 = 2,472,960 -> ends 35,179,520
#define OFF_M2   18944000ull    // reuses T1 (dead after k_dft_w); 9,469,952 -> ends 28,413,952
#define OFF_M3   28413952ull    // 8*68*192*32 float2 = 26,738,688 -> ends 55,152,640 (T1/T2 dead)
#define T1PART   (BB*NROW*NWC)  // float2 elements per h-pair partial (860,160)

__device__ __forceinline__ float2 cmul(float2 a, float2 b) {
    return make_float2(a.x*b.x - a.y*b.y, a.x*b.y + a.y*b.x);
}

// K0: 192-root twiddle table (double-precision build) + mask row tables.
__global__ __launch_bounds__(192) void k_tables(float2* __restrict__ tab,
                                                int* __restrict__ jmin,
                                                int* __restrict__ rstart) {
    int t = threadIdx.x;
    if (t < 192) {
        double th = (2.0 * M_PI / 192.0) * (double)t;
        double s, c;
        sincos(th, &s, &c);
        tab[t] = make_float2((float)c, (float)s);   // e^{+2pi i t/192}
    }
    __shared__ int cnt_s[NBI], jmn_s[NBI];
    if (t < NBI) {
        int ii = ROW0 + t;
        int a = 2*ii - 191;
        int rem = MASK_T - a*a;           // always >= 0 for rows 62..129
        int q = (int)sqrtf((float)rem);
        while ((q+1)*(q+1) <= rem) q++;
        while (q > 0 && q*q > rem) q--;
        jmn_s[t] = (192 - q) >> 1;                        // ceil((191-q)/2)
        cnt_s[t] = ((191 + q) >> 1) - ((192 - q) >> 1) + 1;
    }
    __syncthreads();
    if (t == 0) {
        int acc = 0;
        for (int i = 0; i < NBI; i++) {
            rstart[i] = acc;
            acc += cnt_s[i];
            jmin[i] = jmn_s[i];
        }
        // acc == 3576 (= N_ACTIVE / (C*F)), verified analytically.
    }
}

// K1: scatter the flat weights into the 68x68 box AND fold in the C-forward-DFT
// and F-inverse-DFT:  KQ[c,g] = sum_{sc,f} e^{-2pi i c sc/16} K[sc,f] e^{+2pi i f g/32}
__global__ __launch_bounds__(256) void k_densify(
        const float* __restrict__ kr, const float* __restrict__ ki,
        const float2* __restrict__ tab, const int* __restrict__ jmin,
        const int* __restrict__ rstart, float2* __restrict__ KQ) {
    int blk = blockIdx.x;                 // bi*68 + bj
    int bi = blk / NBI, bj = blk - bi*NBI;
    int tid = threadIdx.x;
    float2* KQo = KQ + (size_t)blk * (CC*FF);
    int a = 2*(ROW0+bi) - 191;
    int bc = 2*(ROW0+bj) - 191;
    bool masked = (a*a + bc*bc) <= MASK_T;   // block-uniform
    if (!masked) {
        for (int e = tid; e < CC*FF; e += 256) KQo[e] = make_float2(0.f, 0.f);
        return;
    }
    __shared__ float2 Kc[CC][FF+1];
    __shared__ float2 Kt[CC][FF+1];
    __shared__ float2 tl[192];
    for (int e = tid; e < 192; e += 256) tl[e] = tab[e];
    int rank = rstart[bi] + ((ROW0+bj) - jmin[bi]);
    size_t base = (size_t)rank * (CC*FF);
    for (int e = tid; e < CC*FF; e += 256)
        Kc[e>>5][e&31] = make_float2(kr[base+e], ki[base+e]);
    __syncthreads();
    for (int e = tid; e < CC*FF; e += 256) {      // Kt[cp][f] = DFT16_c
        int cp = e >> 5, f = e & 31;
        float2 acc = make_float2(0.f, 0.f);
        #pragma unroll
        for (int c = 0; c < CC; c++) {
            int tt = (12*c*cp) % 192;             // 2pi/16 = 2pi*12/192
            float2 w = tl[tt];
            float2 v = Kc[c][f];
            acc.x += v.x*w.x + v.y*w.y;           // v * conj(w)
            acc.y += v.y*w.x - v.x*w.y;
        }
        Kt[cp][f] = acc;
    }
    __syncthreads();
    for (int e = tid; e < CC*FF; e += 256) {      // KQ[cp][g] = iDFT32_f
        int cp = e >> 5, g = e & 31;
        float2 acc = make_float2(0.f, 0.f);
        #pragma unroll
        for (int f = 0; f < FF; f++) {
            int tt = (6*f*g) % 192;               // 2pi/32 = 2pi*6/192
            float2 w = tl[tt];
            float2 v = Kt[cp][f];
            acc.x += v.x*w.x - v.y*w.y;           // v * w
            acc.y += v.x*w.y + v.y*w.x;
        }
        KQo[cp*FF + g] = acc;
    }
}

// K_A: partial forward DFT over H at s = 0..34, radix-2 over h:
// T1(s) = sum_{h=0}^{95} (in[h] + (-1)^s in[h+96]) e^{-2pi i s h/192}
// T1[part][b][row][w][c]: part covers h-pairs [48*part, 48*part+48).
__global__ __launch_bounds__(256) void k_dft_h(
        const float* __restrict__ in, const float2* __restrict__ tab,
        float2* __restrict__ T1) {
    int bg = blockIdx.x;          // 0..8, 4 rows each (row 35 padded off)
    int b  = blockIdx.y;
    int zc = blockIdx.z;          // quarter*NPART + part
    int z  = zc >> 1;
    int part = zc & 1;
    int h0 = part * 48;
    int tid = threadIdx.x;
    const float* inb = in + (size_t)b * HH * NWC;
    int wc0 = z * 768 + tid;
    float2 tw[4], r[4];
    #pragma unroll
    for (int u = 0; u < 4; u++) {
        int row = bg*4 + u;
        int s = row < NROW ? row : 0;
        float2 tv = tab[s];
        r[u] = make_float2(tv.x, -tv.y);          // e^{-2pi i s/192}
        float2 t0 = tab[(s*h0) % 192];
        tw[u] = make_float2(t0.x, -t0.y);         // e^{-2pi i s h0/192}
    }
    float2 acc[4][3];
    #pragma unroll
    for (int u = 0; u < 4; u++)
        #pragma unroll
        for (int k = 0; k < 3; k++) acc[u][k] = make_float2(0.f, 0.f);
    for (int h = h0; h < h0 + 48; h++) {
        const float* rowp = inb + (size_t)h * NWC + wc0;
        const float* pr   = rowp + 96 * NWC;
        float v0 = rowp[0],  v1 = rowp[256],  v2 = rowp[512];
        float w0 = pr[0],    w1 = pr[256],    w2 = pr[512];
        float up0 = v0 + w0, up1 = v1 + w1, up2 = v2 + w2;
        float um0 = v0 - w0, um1 = v1 - w1, um2 = v2 - w2;
        // u even -> row even -> plus class; u odd -> minus class (bg*4 even)
        acc[0][0].x += up0*tw[0].x; acc[0][0].y += up0*tw[0].y;
        acc[0][1].x += up1*tw[0].x; acc[0][1].y += up1*tw[0].y;
        acc[0][2].x += up2*tw[0].x; acc[0][2].y += up2*tw[0].y;
        tw[0] = cmul(tw[0], r[0]);
        acc[1][0].x += um0*tw[1].x; acc[1][0].y += um0*tw[1].y;
        acc[1][1].x += um1*tw[1].x; acc[1][1].y += um1*tw[1].y;
        acc[1][2].x += um2*tw[1].x; acc[1][2].y += um2*tw[1].y;
        tw[1] = cmul(tw[1], r[1]);
        acc[2][0].x += up0*tw[2].x; acc[2][0].y += up0*tw[2].y;
        acc[2][1].x += up1*tw[2].x; acc[2][1].y += up1*tw[2].y;
        acc[2][2].x += up2*tw[2].x; acc[2][2].y += up2*tw[2].y;
        tw[2] = cmul(tw[2], r[2]);
        acc[3][0].x += um0*tw[3].x; acc[3][0].y += um0*tw[3].y;
        acc[3][1].x += um1*tw[3].x; acc[3][1].y += um1*tw[3].y;
        acc[3][2].x += um2*tw[3].x; acc[3][2].y += um2*tw[3].y;
        tw[3] = cmul(tw[3], r[3]);
    }
    #pragma unroll
    for (int u = 0; u < 4; u++) {
        int row = bg*4 + u;
        if (row < NROW) {
            float2* o = T1 + (size_t)part * T1PART + ((size_t)(b*NROW + row)) * NWC + wc0;
            o[0] = acc[u][0]; o[256] = acc[u][1]; o[512] = acc[u][2];
        }
    }
}

// K_B: partial forward DFT over W, radix-2 over w:
// T2(col) = sum_{w=0}^{95} (S[w] +- S[w+96]) e^{-2pi i sj w/192}, class by parity(sj).
// Column dim split 4-ways across blockIdx.z for occupancy.
__global__ __launch_bounds__(256) void k_dft_w(
        const float2* __restrict__ T1, const float2* __restrict__ tab,
        float2* __restrict__ T2) {
    int row = blockIdx.x;             // 0..34
    int b   = blockIdx.y;
    int q   = blockIdx.z;             // col quarter: bases 0,17,35,52
    const int qbase[4] = {0, 17, 35, 52};
    const int qcnt[4]  = {17, 18, 17, 17};
    int base = qbase[q], cnt = qcnt[q];
    int tid = threadIdx.x;
    __shared__ float2 shp[96][CC];    // 12 KB  (S[w] + S[w+96])
    __shared__ float2 shm[96][CC];    // 12 KB  (S[w] - S[w+96])
    const float2* src = T1 + ((size_t)(b*NROW + row)) * NWC;
    for (int e = tid; e < 96*CC; e += 256) {
        float2 a0 = src[e];
        float2 a1 = src[e + T1PART];
        float2 b0 = src[e + 96*CC];
        float2 b1 = src[e + 96*CC + T1PART];
        float Sx = a0.x + a1.x, Sy = a0.y + a1.y;
        float Tx = b0.x + b1.x, Ty = b0.y + b1.y;
        shp[e>>4][e&15] = make_float2(Sx + Tx, Sy + Ty);
        shm[e>>4][e&15] = make_float2(Sx - Tx, Sy - Ty);
    }
    __syncthreads();
    int c = tid >> 4;                 // 0..15
    int bjL = tid & 15;               // 0..15
    // parity(col) = (base + bjL + 16k)&1 = (base + bjL)&1 (constant over k)
    const float2* shsel = ((base + bjL) & 1) ? &shm[0][0] : &shp[0][0];
    float2 tw[2], r[2], acc[2];
    #pragma unroll
    for (int k = 0; k < 2; k++) {
        int off = bjL + 16*k;
        int col = base + off;
        bool valid = off < cnt;
        int sj = (valid ? col : 34) - 34;
        tw[k] = make_float2(1.f, 0.f);
        acc[k] = make_float2(0.f, 0.f);
        int ts = ((sj % 192) + 192) % 192;
        float2 tv = tab[ts];
        r[k] = make_float2(tv.x, -tv.y);
    }
    for (int w = 0; w < 96; w++) {
        float2 av = shsel[w*CC + c];
        #pragma unroll
        for (int k = 0; k < 2; k++) {
            acc[k].x += av.x*tw[k].x - av.y*tw[k].y;
            acc[k].y += av.x*tw[k].y + av.y*tw[k].x;
            tw[k] = cmul(tw[k], r[k]);
        }
    }
    float2* dst = T2 + ((size_t)((b*NROW + row)*NCOL)) * CC;
    #pragma unroll
    for (int k = 0; k < 2; k++) {
        int off = bjL + 16*k;
        int col = base + off;
        if (off < cnt) dst[col*CC + c] = acc[k];
    }
}

// K_M: per-site 16->32 complex matvec; negative-s rows read the conj mirror.
__global__ __launch_bounds__(256) void k_mix(
        const float2* __restrict__ T2, const float2* __restrict__ KQ,
        float2* __restrict__ M2) {
    int site = blockIdx.x;            // bi*68 + bj
    int bi = site / NBI, bj = site - bi*NBI;
    int tid = threadIdx.x;
    int b = tid >> 5;                 // 8 groups of 32 lanes
    int g = tid & 31;
    int row, col;
    bool cj;
    if (bi >= 34) { row = bi - 34; col = bj;      cj = false; }
    else          { row = 34 - bi; col = 68 - bj; cj = true;  }
    const float2* x  = T2 + ((size_t)(b*NROW + row) * NCOL + col) * CC;
    const float2* kq = KQ + (size_t)site * (CC*FF);
    float sgn = cj ? -1.f : 1.f;
    float2 acc = make_float2(0.f, 0.f);
    #pragma unroll
    for (int cp = 0; cp < CC; cp++) {
        float2 xv = x[cp];
        xv.y *= sgn;
        float2 kv = kq[cp*FF + g];
        acc.x += xv.x*kv.x - xv.y*kv.y;
        acc.y += xv.x*kv.y + xv.y*kv.x;
    }
    M2[((size_t)b * (NBI*NBI) + site) * FF + g] = acc;
}

// K_E2: inverse DFT over W, streaming + radix-2 over y + 2 y-values/thread.
// Each loaded M2 pair (bj, bj+1) feeds TWO independent twiddle chains (y0,
// y0+24): 16 MACs per 4 loads (2x arithmetic intensity, 2x ILP) and a 1-deep
// software prefetch so the vmcnt wait overlaps the current pair's MACs.
// M3 layout: [b][bi][y][g]; stores coalesced float4.
__global__ __launch_bounds__(192) void k_idft_w(
        const float2* __restrict__ M2, const float2* __restrict__ tab,
        float2* __restrict__ M3) {
    int bi = blockIdx.x;
    int b  = blockIdx.y;
    int tid = threadIdx.x;
    int g0 = (tid & 7) * 4;                  // 0,4,...,28
    int ty = tid >> 3;                       // 0..23
    int y0 = blockIdx.z * 48 + ty;           // z in {0,1}
    int y1 = y0 + 24;
    const float2* m2 = M2 + ((size_t)b*(NBI*NBI) + (size_t)bi*NBI) * FF + g0;
    float2 twA = tab[(158*y0) % 192], rrA = tab[y0];
    float2 twB = tab[(158*y1) % 192], rrB = tab[y1];
    float2 z0 = make_float2(0.f, 0.f);
    float2 eA0=z0,eA1=z0,eA2=z0,eA3=z0, oA0=z0,oA1=z0,oA2=z0,oA3=z0;
    float2 eB0=z0,eB1=z0,eB2=z0,eB3=z0, oB0=z0,oB1=z0,oB2=z0,oB3=z0;
    float4 f0 = *reinterpret_cast<const float4*>(m2);
    float4 f1 = *reinterpret_cast<const float4*>(m2 + 2);
    float4 h0 = *reinterpret_cast<const float4*>(m2 + FF);
    float4 h1 = *reinterpret_cast<const float4*>(m2 + FF + 2);
    for (int bj = 0; bj < NBI; bj += 2) {
        int bjn = min(bj + 2, NBI - 2);      // clamped prefetch (branch-free)
        const float2* np = m2 + (size_t)bjn * FF;
        float4 nf0 = *reinterpret_cast<const float4*>(np);
        float4 nf1 = *reinterpret_cast<const float4*>(np + 2);
        float4 nh0 = *reinterpret_cast<const float4*>(np + FF);
        float4 nh1 = *reinterpret_cast<const float4*>(np + FF + 2);
        // chain A (y0): even row (bj) then odd row (bj+1)
        eA0.x += f0.x*twA.x - f0.y*twA.y;  eA0.y += f0.x*twA.y + f0.y*twA.x;
        eA1.x += f0.z*twA.x - f0.w*twA.y;  eA1.y += f0.z*twA.y + f0.w*twA.x;
        eA2.x += f1.x*twA.x - f1.y*twA.y;  eA2.y += f1.x*twA.y + f1.y*twA.x;
        eA3.x += f1.z*twA.x - f1.w*twA.y;  eA3.y += f1.z*twA.y + f1.w*twA.x;
        twA = cmul(twA, rrA);
        oA0.x += h0.x*twA.x - h0.y*twA.y;  oA0.y += h0.x*twA.y + h0.y*twA.x;
        oA1.x += h0.z*twA.x - h0.w*twA.y;  oA1.y += h0.z*twA.y + h0.w*twA.x;
        oA2.x += h1.x*twA.x - h1.y*twA.y;  oA2.y += h1.x*twA.y + h1.y*twA.x;
        oA3.x += h1.z*twA.x - h1.w*twA.y;  oA3.y += h1.z*twA.y + h1.w*twA.x;
        twA = cmul(twA, rrA);
        // chain B (y1): same data, independent twiddle chain
        eB0.x += f0.x*twB.x - f0.y*twB.y;  eB0.y += f0.x*twB.y + f0.y*twB.x;
        eB1.x += f0.z*twB.x - f0.w*twB.y;  eB1.y += f0.z*twB.y + f0.w*twB.x;
        eB2.x += f1.x*twB.x - f1.y*twB.y;  eB2.y += f1.x*twB.y + f1.y*twB.x;
        eB3.x += f1.z*twB.x - f1.w*twB.y;  eB3.y += f1.z*twB.y + f1.w*twB.x;
        twB = cmul(twB, rrB);
        oB0.x += h0.x*twB.x - h0.y*twB.y;  oB0.y += h0.x*twB.y + h0.y*twB.x;
        oB1.x += h0.z*twB.x - h0.w*twB.y;  oB1.y += h0.z*twB.y + h0.w*twB.x;
        oB2.x += h1.x*twB.x - h1.y*twB.y;  oB2.y += h1.x*twB.y + h1.y*twB.x;
        oB3.x += h1.z*twB.x - h1.w*twB.y;  oB3.y += h1.z*twB.y + h1.w*twB.x;
        twB = cmul(twB, rrB);
        f0 = nf0; f1 = nf1; h0 = nh0; h1 = nh1;
    }
    float2* oa = M3 + (((size_t)(b*NBI + bi))*HH + y0)*FF + g0;
    *reinterpret_cast<float4*>(oa)     = make_float4(eA0.x+oA0.x, eA0.y+oA0.y, eA1.x+oA1.x, eA1.y+oA1.y);
    *reinterpret_cast<float4*>(oa + 2) = make_float4(eA2.x+oA2.x, eA2.y+oA2.y, eA3.x+oA3.x, eA3.y+oA3.y);
    float2* ob = oa + 96*FF;
    *reinterpret_cast<float4*>(ob)     = make_float4(eA0.x-oA0.x, eA0.y-oA0.y, eA1.x-oA1.x, eA1.y-oA1.y);
    *reinterpret_cast<float4*>(ob + 2) = make_float4(eA2.x-oA2.x, eA2.y-oA2.y, eA3.x-oA3.x, eA3.y-oA3.y);
    float2* oc = oa + 24*FF;   // y1
    *reinterpret_cast<float4*>(oc)     = make_float4(eB0.x+oB0.x, eB0.y+oB0.y, eB1.x+oB1.x, eB1.y+oB1.y);
    *reinterpret_cast<float4*>(oc + 2) = make_float4(eB2.x+oB2.x, eB2.y+oB2.y, eB3.x+oB3.x, eB3.y+oB3.y);
    float2* od = oc + 96*FF;
    *reinterpret_cast<float4*>(od)     = make_float4(eB0.x-oB0.x, eB0.y-oB0.y, eB1.x-oB1.x, eB1.y-oB1.y);
    *reinterpret_cast<float4*>(od + 2) = make_float4(eB2.x-oB2.x, eB2.y-oB2.y, eB3.x-oB3.x, eB3.y-oB3.y);
}

// K_E3: inverse DFT over H keeping Re only, Hermitian (s,-s) pairing AND
// radix-2 over x: even/odd-p accumulators give out(x) = E+O, out(x+96) = E-O.
// comb[p][g] = (A,B):  contribution = A*cos(2pi p x/192) - B*sin(...).
__global__ __launch_bounds__(256) void k_idft_h(
        const float2* __restrict__ M3, const float2* __restrict__ tab,
        float* __restrict__ out) {
    int y = blockIdx.x;
    int b = blockIdx.y;
    int tid = threadIdx.x;
    __shared__ __align__(16) float2 comb[NROW][FF];   // (A,B) per pair, 8.96 KB
    for (int e = tid; e < NROW*FF; e += 256) {
        int p = e >> 5, g = e & 31;
        float A, Bv;
        if (p == 0) {
            float2 v = M3[(((size_t)(b*NBI + 34))*HH + y)*FF + g];
            A = v.x; Bv = 0.f;
        } else if (p == 34) {
            float2 v = M3[(((size_t)(b*NBI + 0))*HH + y)*FF + g];
            A = v.x; Bv = -v.y;
        } else {
            float2 vp = M3[(((size_t)(b*NBI + 34 + p))*HH + y)*FF + g];
            float2 vm = M3[(((size_t)(b*NBI + 34 - p))*HH + y)*FF + g];
            A = vp.x + vm.x; Bv = vp.y - vm.y;
        }
        comb[p][g] = make_float2(A, Bv);
    }
    __syncthreads();
    int tx = tid >> 3;          // 0..31  (3 x-pairs per thread: x = tx*3+j)
    int tg = tid & 7;
    int g0 = tg * 4;
    float2 tw[3], rr[3];
    float ae[3][4], ao[3][4];
    #pragma unroll
    for (int j = 0; j < 3; j++) {
        int x = tx*3 + j;
        tw[j] = make_float2(1.f, 0.f);   // angle p=0
        rr[j] = tab[x];                  // e^{+2pi i x/192} per p step
        #pragma unroll
        for (int q = 0; q < 4; q++) { ae[j][q] = 0.f; ao[j][q] = 0.f; }
    }
    for (int p = 0; p < 34; p += 2) {
        float4 f0 = *reinterpret_cast<const float4*>(&comb[p][g0]);     // A0,B0,A1,B1
        float4 f1 = *reinterpret_cast<const float4*>(&comb[p][g0+2]);   // A2,B2,A3,B3
        #pragma unroll
        for (int j = 0; j < 3; j++) {
            float2 t = tw[j];
            ae[j][0] += f0.x*t.x - f0.y*t.y;
            ae[j][1] += f0.z*t.x - f0.w*t.y;
            ae[j][2] += f1.x*t.x - f1.y*t.y;
            ae[j][3] += f1.z*t.x - f1.w*t.y;
            tw[j] = cmul(t, rr[j]);
        }
        float4 h0 = *reinterpret_cast<const float4*>(&comb[p+1][g0]);
        float4 h1 = *reinterpret_cast<const float4*>(&comb[p+1][g0+2]);
        #pragma unroll
        for (int j = 0; j < 3; j++) {
            float2 t = tw[j];
            ao[j][0] += h0.x*t.x - h0.y*t.y;
            ao[j][1] += h0.z*t.x - h0.w*t.y;
            ao[j][2] += h1.x*t.x - h1.y*t.y;
            ao[j][3] += h1.z*t.x - h1.w*t.y;
            tw[j] = cmul(t, rr[j]);
        }
    }
    {   // tail p = 34 (even)
        float4 f0 = *reinterpret_cast<const float4*>(&comb[34][g0]);
        float4 f1 = *reinterpret_cast<const float4*>(&comb[34][g0+2]);
        #pragma unroll
        for (int j = 0; j < 3; j++) {
            float2 t = tw[j];
            ae[j][0] += f0.x*t.x - f0.y*t.y;
            ae[j][1] += f0.z*t.x - f0.w*t.y;
            ae[j][2] += f1.x*t.x - f1.y*t.y;
            ae[j][3] += f1.z*t.x - f1.w*t.y;
        }
    }
    #pragma unroll
    for (int j = 0; j < 3; j++) {
        int x = tx*3 + j;
        float4 oA, oB;
        oA.x = (ae[j][0]+ao[j][0])*SCALE; oA.y = (ae[j][1]+ao[j][1])*SCALE;
        oA.z = (ae[j][2]+ao[j][2])*SCALE; oA.w = (ae[j][3]+ao[j][3])*SCALE;
        oB.x = (ae[j][0]-ao[j][0])*SCALE; oB.y = (ae[j][1]-ao[j][1])*SCALE;
        oB.z = (ae[j][2]-ao[j][2])*SCALE; oB.w = (ae[j][3]-ao[j][3])*SCALE;
        *reinterpret_cast<float4*>(&out[(((size_t)(b*HH + x)) * WW + y) * FF + g0]) = oA;
        *reinterpret_cast<float4*>(&out[(((size_t)(b*HH + x + 96)) * WW + y) * FF + g0]) = oB;
    }
}

extern "C" void kernel_launch(void* const* d_in, const int* in_sizes, int n_in,
                              void* d_out, int out_size, void* d_ws, size_t ws_size,
                              hipStream_t stream) {
    const float* in = (const float*)d_in[0];
    const float* kr = (const float*)d_in[1];
    const float* ki = (const float*)d_in[2];
    float* out = (float*)d_out;
    char* ws = (char*)d_ws;
    float2* tab = (float2*)(ws + OFF_TAB);
    int* jmin   = (int*)(ws + OFF_JMIN);
    int* rst    = (int*)(ws + OFF_RST);
    float2* KQ  = (float2*)(ws + OFF_KQ);
    float2* T1  = (float2*)(ws + OFF_T1);
    float2* T2  = (float2*)(ws + OFF_T2);
    float2* M2  = (float2*)(ws + OFF_M2);   // aliases T1 (dead by then)
    float2* M3  = (float2*)(ws + OFF_M3);   // overlaps T2 (dead by then)

    k_tables <<<1, 192, 0, stream>>>(tab, jmin, rst);
    k_densify<<<NBI*NBI, 256, 0, stream>>>(kr, ki, tab, jmin, rst, KQ);
    k_dft_h  <<<dim3(9, BB, 4*NPART), 256, 0, stream>>>(in, tab, T1);
    k_dft_w  <<<dim3(NROW, BB, 4), 256, 0, stream>>>(T1, tab, T2);
    k_mix    <<<NBI*NBI, 256, 0, stream>>>(T2, KQ, M2);
    k_idft_w <<<dim3(NBI, BB, 2), 192, 0, stream>>>(M2, tab, M3);
    k_idft_h <<<dim3(HH, BB), 256, 0, stream>>>(M3, tab, out);
}